// Round 1
// baseline (622.447 us; speedup 1.0000x reference)
//
#include <hip/hip_runtime.h>

typedef __attribute__((ext_vector_type(4))) float float4v;
typedef __attribute__((ext_vector_type(8))) short short8v;

__device__ __forceinline__ unsigned short f2bf(float f) {
  union { float f; unsigned int u; } v; v.f = f;
  unsigned int u = v.u;
  unsigned int r = (u + 0x7FFFu + ((u >> 16) & 1u)) >> 16;
  return (unsigned short)r;
}

// Main kernel: per tile of 4 sampled points (64 rows), gather x=[feat|xyz|0]
// into LDS as bf16 [64][104], MFMA vs W^T fragments (held in regs), then
// per-(point,channel) max/min and per-block BN partial sums.
__global__ __launch_bounds__(256) void td_main(
    const float* __restrict__ point, const float* __restrict__ feat,
    const float* __restrict__ W, const int* __restrict__ sample_idx,
    const int* __restrict__ knn_idx,
    float* __restrict__ ymax_out, float* __restrict__ ymin_out,
    float* __restrict__ partials, int nTiles, int has_ymin)
{
  __shared__ __align__(16) char smem[24576];
  unsigned short* wt = (unsigned short*)smem;   // phase 0: [128][96] bf16 W^T
  unsigned short* A  = (unsigned short*)smem;   // phase 1: [64][104] bf16 x-tile
  int*   knn_lds = (int*)(smem + 13312);        // [64]
  float* spt     = (float*)(smem + 13568);      // [12] sampled-point coords

  const int tid  = threadIdx.x;
  const int lane = tid & 63;
  const int wv   = tid >> 6;       // wave 0..3 -> output cols wv*32..+31
  const int l15  = lane & 15;
  const int lg   = lane >> 4;

  // Build W^T bf16 with permuted K: c'<64 -> W[3+c'][d]; 64..66 -> W[c'-64][d]; else 0
  for (int i = tid; i < 128 * 96; i += 256) {
    int d = i / 96;
    int c = i - d * 96;
    float v = 0.f;
    if (c < 64)      v = W[(size_t)(3 + c) * 128 + d];
    else if (c < 67) v = W[(size_t)(c - 64) * 128 + d];
    wt[i] = f2bf(v);
  }
  __syncthreads();

  short8v bfrag[2][3];
  for (int ni = 0; ni < 2; ++ni)
    for (int kk = 0; kk < 3; ++kk) {
      int row = wv * 32 + ni * 16 + l15;          // output channel d
      int col = kk * 32 + (lg << 3);              // k offset
      bfrag[ni][kk] = *(const short8v*)&wt[row * 96 + col];
    }

  float sum0 = 0.f, sum1 = 0.f, sq0 = 0.f, sq1 = 0.f;

  for (int t = blockIdx.x; t < nTiles; t += gridDim.x) {
    const int p0 = t * 4;
    const int r0 = t * 64;
    __syncthreads();  // protect LDS (incl. wt region on first iter) from prior readers
    if (tid < 64) knn_lds[tid] = knn_idx[r0 + tid];
    if (tid < 12) {
      int pi = tid / 3;
      int c  = tid - pi * 3;
      spt[tid] = point[(size_t)sample_idx[p0 + pi] * 3 + c];
    }
    __syncthreads();

    // feat gather -> bf16 -> LDS cols 0..63 (16 floats per thread)
    {
      int row = tid >> 2;
      int seg = (tid & 3) << 4;
      const float* src = feat + (size_t)knn_lds[row] * 64 + seg;
      float4v f0 = *(const float4v*)(src + 0);
      float4v f1 = *(const float4v*)(src + 4);
      float4v f2 = *(const float4v*)(src + 8);
      float4v f3 = *(const float4v*)(src + 12);
      short8v lo, hi;
      lo[0] = (short)f2bf(f0[0]); lo[1] = (short)f2bf(f0[1]);
      lo[2] = (short)f2bf(f0[2]); lo[3] = (short)f2bf(f0[3]);
      lo[4] = (short)f2bf(f1[0]); lo[5] = (short)f2bf(f1[1]);
      lo[6] = (short)f2bf(f1[2]); lo[7] = (short)f2bf(f1[3]);
      hi[0] = (short)f2bf(f2[0]); hi[1] = (short)f2bf(f2[1]);
      hi[2] = (short)f2bf(f2[2]); hi[3] = (short)f2bf(f2[3]);
      hi[4] = (short)f2bf(f3[0]); hi[5] = (short)f2bf(f3[1]);
      hi[6] = (short)f2bf(f3[2]); hi[7] = (short)f2bf(f3[3]);
      unsigned short* dst = A + row * 104 + seg;
      *(short8v*)(dst)     = lo;
      *(short8v*)(dst + 8) = hi;
    }
    // xyz diffs -> cols 64..66, zeros -> cols 67..95
    if (tid < 64) {
      int g  = knn_lds[tid];
      int pi = tid >> 4;
      float d0 = point[(size_t)g * 3 + 0] - spt[pi * 3 + 0];
      float d1 = point[(size_t)g * 3 + 1] - spt[pi * 3 + 1];
      float d2 = point[(size_t)g * 3 + 2] - spt[pi * 3 + 2];
      short8v xz = {0, 0, 0, 0, 0, 0, 0, 0};
      xz[0] = (short)f2bf(d0); xz[1] = (short)f2bf(d1); xz[2] = (short)f2bf(d2);
      short8v zz = {0, 0, 0, 0, 0, 0, 0, 0};
      unsigned short* dst = A + tid * 104 + 64;
      *(short8v*)(dst)      = xz;
      *(short8v*)(dst + 8)  = zz;
      *(short8v*)(dst + 16) = zz;
      *(short8v*)(dst + 24) = zz;
    }
    __syncthreads();

    float4v acc[4][2];
    for (int mi = 0; mi < 4; ++mi)
      for (int ni = 0; ni < 2; ++ni)
        acc[mi][ni] = (float4v){0.f, 0.f, 0.f, 0.f};

    for (int mi = 0; mi < 4; ++mi) {
      const unsigned short* ar = A + (mi * 16 + l15) * 104 + (lg << 3);
      short8v a0 = *(const short8v*)(ar);
      short8v a1 = *(const short8v*)(ar + 32);
      short8v a2 = *(const short8v*)(ar + 64);
      for (int ni = 0; ni < 2; ++ni) {
        acc[mi][ni] = __builtin_amdgcn_mfma_f32_16x16x32_bf16(a0, bfrag[ni][0], acc[mi][ni], 0, 0, 0);
        acc[mi][ni] = __builtin_amdgcn_mfma_f32_16x16x32_bf16(a1, bfrag[ni][1], acc[mi][ni], 0, 0, 0);
        acc[mi][ni] = __builtin_amdgcn_mfma_f32_16x16x32_bf16(a2, bfrag[ni][2], acc[mi][ni], 0, 0, 0);
      }
    }

    // stats + per-point max/min over k=16 rows
    for (int mi = 0; mi < 4; ++mi) {
      for (int ni = 0; ni < 2; ++ni) {
        float4v v = acc[mi][ni];
        float s = v[0] + v[1] + v[2] + v[3];
        float q = v[0] * v[0] + v[1] * v[1] + v[2] * v[2] + v[3] * v[3];
        if (ni == 0) { sum0 += s; sq0 += q; } else { sum1 += s; sq1 += q; }
        float mx = fmaxf(fmaxf(v[0], v[1]), fmaxf(v[2], v[3]));
        float mn = fminf(fminf(v[0], v[1]), fminf(v[2], v[3]));
        mx = fmaxf(mx, __shfl_xor(mx, 16));
        mx = fmaxf(mx, __shfl_xor(mx, 32));
        mn = fminf(mn, __shfl_xor(mn, 16));
        mn = fminf(mn, __shfl_xor(mn, 32));
        if (lane < 16) {
          size_t o = (size_t)(p0 + mi) * 128 + wv * 32 + ni * 16 + lane;
          ymax_out[o] = mx;
          if (has_ymin) ymin_out[o] = mn;
        }
      }
    }
  }

  // deterministic per-block partials: [block][0..127]=sum, [128..255]=sumsq
  sum0 += __shfl_xor(sum0, 16); sum0 += __shfl_xor(sum0, 32);
  sq0  += __shfl_xor(sq0, 16);  sq0  += __shfl_xor(sq0, 32);
  sum1 += __shfl_xor(sum1, 16); sum1 += __shfl_xor(sum1, 32);
  sq1  += __shfl_xor(sq1, 16);  sq1  += __shfl_xor(sq1, 32);
  if (lane < 16) {
    float* pp = partials + (size_t)blockIdx.x * 256;
    pp[wv * 32 + lane]             = sum0;
    pp[128 + wv * 32 + lane]       = sq0;
    pp[wv * 32 + 16 + lane]        = sum1;
    pp[128 + wv * 32 + 16 + lane]  = sq1;
  }
}

__global__ void td_stats(const float* __restrict__ partials,
                         const float* __restrict__ gamma,
                         const float* __restrict__ beta,
                         float* __restrict__ ab, int G, float invN)
{
  int d = threadIdx.x;  // 128 threads
  float s = 0.f, q = 0.f;
  for (int g = 0; g < G; ++g) {
    s += partials[(size_t)g * 256 + d];
    q += partials[(size_t)g * 256 + 128 + d];
  }
  float mean = s * invN;
  float var  = fmaxf(q * invN - mean * mean, 0.f);
  float a = gamma[d] * rsqrtf(var + 1e-5f);
  float b = beta[d] - mean * a;
  ab[d] = a;
  ab[128 + d] = b;
}

__global__ __launch_bounds__(256) void td_transform(
    float* __restrict__ outf, const float* __restrict__ ymin,
    const float* __restrict__ ab, int total4, int has_ymin)
{
  __shared__ float sab[256];
  sab[threadIdx.x] = ab[threadIdx.x];
  __syncthreads();
  int stride = gridDim.x * blockDim.x;
  for (int i = blockIdx.x * blockDim.x + threadIdx.x; i < total4; i += stride) {
    float4v v = *(const float4v*)(outf + (size_t)i * 4);
    int d0 = (i * 4) & 127;
    if (has_ymin) {
      float4v mn = *(const float4v*)(ymin + (size_t)i * 4);
      #pragma unroll
      for (int j = 0; j < 4; ++j)
        if (sab[d0 + j] < 0.f) v[j] = mn[j];
    }
    #pragma unroll
    for (int j = 0; j < 4; ++j) {
      float z = fmaf(v[j], sab[d0 + j], sab[128 + d0 + j]);
      v[j] = z > 0.f ? z : 0.f;
    }
    *(float4v*)(outf + (size_t)i * 4) = v;
  }
}

__global__ void td_newpoint(const float* __restrict__ point,
                            const int* __restrict__ sidx,
                            float* __restrict__ out, int m)
{
  int i = blockIdx.x * blockDim.x + threadIdx.x;
  if (i < m) {
    size_t s = (size_t)sidx[i];
    out[(size_t)i * 3 + 0] = point[s * 3 + 0];
    out[(size_t)i * 3 + 1] = point[s * 3 + 1];
    out[(size_t)i * 3 + 2] = point[s * 3 + 2];
  }
}

extern "C" void kernel_launch(void* const* d_in, const int* in_sizes, int n_in,
                              void* d_out, int out_size, void* d_ws, size_t ws_size,
                              hipStream_t stream)
{
  const float* point = (const float*)d_in[0];
  const float* feat  = (const float*)d_in[1];
  const float* W     = (const float*)d_in[2];
  const float* gamma = (const float*)d_in[3];
  const float* beta  = (const float*)d_in[4];
  const int* sample_idx = (const int*)d_in[5];
  const int* knn_idx    = (const int*)d_in[6];

  const int m = in_sizes[5];            // 60000
  const int k = in_sizes[6] / m;        // 16
  const int nTiles = m / 4;             // 4 points (64 rows) per tile

  float* out  = (float*)d_out;
  float* newp = out;                    // (m,3)
  float* ymax = out + (size_t)m * 3;    // (m,128) pre-norm max, finished in-place

  // ws layout: [ab 1KB][partials G*1KB][ymin m*512B if it fits]
  char* ws = (char*)d_ws;
  float* ab = (float*)ws;
  int G = (int)((ws_size > 1024 ? ws_size - 1024 : 0) / 1024);
  if (G > 2048) G = 2048;
  if (G < 8) G = 8;
  if (G > nTiles) G = nTiles;
  float* partials = (float*)(ws + 1024);
  size_t off_ymin = 1024 + (size_t)G * 1024;
  int has_ymin = (ws_size >= off_ymin + (size_t)m * 512) ? 1 : 0;
  float* ymin = (float*)(ws + off_ymin);

  td_newpoint<<<(m + 255) / 256, 256, 0, stream>>>(point, sample_idx, newp, m);
  td_main<<<G, 256, 0, stream>>>(point, feat, W, sample_idx, knn_idx,
                                 ymax, ymin, partials, nTiles, has_ymin);
  float invN = 1.0f / ((float)m * (float)k);
  td_stats<<<1, 128, 0, stream>>>(partials, gamma, beta, ab, G, invN);
  td_transform<<<2048, 256, 0, stream>>>(ymax, ymin, ab, m * 128 / 4, has_ymin);
}

// Round 2
// 133.438 us; speedup vs baseline: 4.6647x; 4.6647x over previous
//
#include <hip/hip_runtime.h>

typedef __attribute__((ext_vector_type(4))) float float4v;
typedef __attribute__((ext_vector_type(8))) short short8v;

__device__ __forceinline__ unsigned short f2bf(float f) {
  union { float f; unsigned int u; } v; v.f = f;
  unsigned int u = v.u;
  unsigned int r = (u + 0x7FFFu + ((u >> 16) & 1u)) >> 16;
  return (unsigned short)r;
}

// Main kernel: per tile of 4 sampled points (64 rows), gather x=[feat|xyz|0]
// into LDS as bf16 [64][104], MFMA vs W^T fragments (held in regs), then
// per-(point,channel) max/min and per-block BN partial sums.
__global__ __launch_bounds__(256) void td_main(
    const float* __restrict__ point, const float* __restrict__ feat,
    const float* __restrict__ W, const int* __restrict__ sample_idx,
    const int* __restrict__ knn_idx,
    float* __restrict__ ymax_out, float* __restrict__ ymin_out,
    float* __restrict__ partials, int nTiles, int has_ymin)
{
  __shared__ __align__(16) char smem[24576];
  unsigned short* wt = (unsigned short*)smem;   // phase 0: [128][96] bf16 W^T
  unsigned short* A  = (unsigned short*)smem;   // phase 1: [64][104] bf16 x-tile
  int*   knn_lds = (int*)(smem + 13312);        // [64]
  float* spt     = (float*)(smem + 13568);      // [12] sampled-point coords

  const int tid  = threadIdx.x;
  const int lane = tid & 63;
  const int wv   = tid >> 6;       // wave 0..3 -> output cols wv*32..+31
  const int l15  = lane & 15;
  const int lg   = lane >> 4;

  // Build W^T bf16 with permuted K: c'<64 -> W[3+c'][d]; 64..66 -> W[c'-64][d]; else 0
  for (int i = tid; i < 128 * 96; i += 256) {
    int d = i / 96;
    int c = i - d * 96;
    float v = 0.f;
    if (c < 64)      v = W[(size_t)(3 + c) * 128 + d];
    else if (c < 67) v = W[(size_t)(c - 64) * 128 + d];
    wt[i] = f2bf(v);
  }
  __syncthreads();

  short8v bfrag[2][3];
  for (int ni = 0; ni < 2; ++ni)
    for (int kk = 0; kk < 3; ++kk) {
      int row = wv * 32 + ni * 16 + l15;          // output channel d
      int col = kk * 32 + (lg << 3);              // k offset
      bfrag[ni][kk] = *(const short8v*)&wt[row * 96 + col];
    }

  float sum0 = 0.f, sum1 = 0.f, sq0 = 0.f, sq1 = 0.f;

  for (int t = blockIdx.x; t < nTiles; t += gridDim.x) {
    const int p0 = t * 4;
    const int r0 = t * 64;
    __syncthreads();  // protect LDS (incl. wt region on first iter) from prior readers
    if (tid < 64) knn_lds[tid] = knn_idx[r0 + tid];
    if (tid < 12) {
      int pi = tid / 3;
      int c  = tid - pi * 3;
      spt[tid] = point[(size_t)sample_idx[p0 + pi] * 3 + c];
    }
    __syncthreads();

    // feat gather -> bf16 -> LDS cols 0..63 (16 floats per thread)
    {
      int row = tid >> 2;
      int seg = (tid & 3) << 4;
      const float* src = feat + (size_t)knn_lds[row] * 64 + seg;
      float4v f0 = *(const float4v*)(src + 0);
      float4v f1 = *(const float4v*)(src + 4);
      float4v f2 = *(const float4v*)(src + 8);
      float4v f3 = *(const float4v*)(src + 12);
      short8v lo, hi;
      lo[0] = (short)f2bf(f0[0]); lo[1] = (short)f2bf(f0[1]);
      lo[2] = (short)f2bf(f0[2]); lo[3] = (short)f2bf(f0[3]);
      lo[4] = (short)f2bf(f1[0]); lo[5] = (short)f2bf(f1[1]);
      lo[6] = (short)f2bf(f1[2]); lo[7] = (short)f2bf(f1[3]);
      hi[0] = (short)f2bf(f2[0]); hi[1] = (short)f2bf(f2[1]);
      hi[2] = (short)f2bf(f2[2]); hi[3] = (short)f2bf(f2[3]);
      hi[4] = (short)f2bf(f3[0]); hi[5] = (short)f2bf(f3[1]);
      hi[6] = (short)f2bf(f3[2]); hi[7] = (short)f2bf(f3[3]);
      unsigned short* dst = A + row * 104 + seg;
      *(short8v*)(dst)     = lo;
      *(short8v*)(dst + 8) = hi;
    }
    // xyz diffs -> cols 64..66, zeros -> cols 67..95
    if (tid < 64) {
      int g  = knn_lds[tid];
      int pi = tid >> 4;
      float d0 = point[(size_t)g * 3 + 0] - spt[pi * 3 + 0];
      float d1 = point[(size_t)g * 3 + 1] - spt[pi * 3 + 1];
      float d2 = point[(size_t)g * 3 + 2] - spt[pi * 3 + 2];
      short8v xz = {0, 0, 0, 0, 0, 0, 0, 0};
      xz[0] = (short)f2bf(d0); xz[1] = (short)f2bf(d1); xz[2] = (short)f2bf(d2);
      short8v zz = {0, 0, 0, 0, 0, 0, 0, 0};
      unsigned short* dst = A + tid * 104 + 64;
      *(short8v*)(dst)      = xz;
      *(short8v*)(dst + 8)  = zz;
      *(short8v*)(dst + 16) = zz;
      *(short8v*)(dst + 24) = zz;
    }
    __syncthreads();

    float4v acc[4][2];
    for (int mi = 0; mi < 4; ++mi)
      for (int ni = 0; ni < 2; ++ni)
        acc[mi][ni] = (float4v){0.f, 0.f, 0.f, 0.f};

    for (int mi = 0; mi < 4; ++mi) {
      const unsigned short* ar = A + (mi * 16 + l15) * 104 + (lg << 3);
      short8v a0 = *(const short8v*)(ar);
      short8v a1 = *(const short8v*)(ar + 32);
      short8v a2 = *(const short8v*)(ar + 64);
      for (int ni = 0; ni < 2; ++ni) {
        acc[mi][ni] = __builtin_amdgcn_mfma_f32_16x16x32_bf16(a0, bfrag[ni][0], acc[mi][ni], 0, 0, 0);
        acc[mi][ni] = __builtin_amdgcn_mfma_f32_16x16x32_bf16(a1, bfrag[ni][1], acc[mi][ni], 0, 0, 0);
        acc[mi][ni] = __builtin_amdgcn_mfma_f32_16x16x32_bf16(a2, bfrag[ni][2], acc[mi][ni], 0, 0, 0);
      }
    }

    // stats + per-point max/min over k=16 rows
    for (int mi = 0; mi < 4; ++mi) {
      for (int ni = 0; ni < 2; ++ni) {
        float4v v = acc[mi][ni];
        float s = v[0] + v[1] + v[2] + v[3];
        float q = v[0] * v[0] + v[1] * v[1] + v[2] * v[2] + v[3] * v[3];
        if (ni == 0) { sum0 += s; sq0 += q; } else { sum1 += s; sq1 += q; }
        float mx = fmaxf(fmaxf(v[0], v[1]), fmaxf(v[2], v[3]));
        float mn = fminf(fminf(v[0], v[1]), fminf(v[2], v[3]));
        mx = fmaxf(mx, __shfl_xor(mx, 16));
        mx = fmaxf(mx, __shfl_xor(mx, 32));
        mn = fminf(mn, __shfl_xor(mn, 16));
        mn = fminf(mn, __shfl_xor(mn, 32));
        if (lane < 16) {
          size_t o = (size_t)(p0 + mi) * 128 + wv * 32 + ni * 16 + lane;
          ymax_out[o] = mx;
          if (has_ymin) ymin_out[o] = mn;
        }
      }
    }
  }

  // deterministic per-block partials: [block][0..127]=sum, [128..255]=sumsq
  sum0 += __shfl_xor(sum0, 16); sum0 += __shfl_xor(sum0, 32);
  sq0  += __shfl_xor(sq0, 16);  sq0  += __shfl_xor(sq0, 32);
  sum1 += __shfl_xor(sum1, 16); sum1 += __shfl_xor(sum1, 32);
  sq1  += __shfl_xor(sq1, 16);  sq1  += __shfl_xor(sq1, 32);
  if (lane < 16) {
    float* pp = partials + (size_t)blockIdx.x * 256;
    pp[wv * 32 + lane]             = sum0;
    pp[128 + wv * 32 + lane]       = sq0;
    pp[wv * 32 + 16 + lane]        = sum1;
    pp[128 + wv * 32 + 16 + lane]  = sq1;
  }
}

// Parallel BN-stats fold: one block per channel, 256 threads strided over G
// partial buffers, deterministic LDS tree reduce (fixed assignment + order).
__global__ __launch_bounds__(256) void td_stats(
    const float* __restrict__ partials,
    const float* __restrict__ gamma,
    const float* __restrict__ beta,
    float* __restrict__ ab, int G, float invN)
{
  __shared__ float ls[256], lq[256];
  const int d = blockIdx.x;     // channel 0..127
  const int t = threadIdx.x;
  float s = 0.f, q = 0.f;
  for (int g = t; g < G; g += 256) {
    s += partials[(size_t)g * 256 + d];
    q += partials[(size_t)g * 256 + 128 + d];
  }
  ls[t] = s; lq[t] = q;
  __syncthreads();
  for (int w = 128; w > 0; w >>= 1) {
    if (t < w) { ls[t] += ls[t + w]; lq[t] += lq[t + w]; }
    __syncthreads();
  }
  if (t == 0) {
    float mean = ls[0] * invN;
    float var  = fmaxf(lq[0] * invN - mean * mean, 0.f);
    float a = gamma[d] * rsqrtf(var + 1e-5f);
    float b = beta[d] - mean * a;
    ab[d] = a;
    ab[128 + d] = b;
  }
}

__global__ __launch_bounds__(256) void td_transform(
    float* __restrict__ outf, const float* __restrict__ ymin,
    const float* __restrict__ ab, int total4, int has_ymin)
{
  __shared__ float sab[256];
  sab[threadIdx.x] = ab[threadIdx.x];
  __syncthreads();
  int stride = gridDim.x * blockDim.x;
  for (int i = blockIdx.x * blockDim.x + threadIdx.x; i < total4; i += stride) {
    float4v v = *(const float4v*)(outf + (size_t)i * 4);
    int d0 = (i * 4) & 127;
    if (has_ymin) {
      float4v mn = *(const float4v*)(ymin + (size_t)i * 4);
      #pragma unroll
      for (int j = 0; j < 4; ++j)
        if (sab[d0 + j] < 0.f) v[j] = mn[j];
    }
    #pragma unroll
    for (int j = 0; j < 4; ++j) {
      float z = fmaf(v[j], sab[d0 + j], sab[128 + d0 + j]);
      v[j] = z > 0.f ? z : 0.f;
    }
    *(float4v*)(outf + (size_t)i * 4) = v;
  }
}

__global__ void td_newpoint(const float* __restrict__ point,
                            const int* __restrict__ sidx,
                            float* __restrict__ out, int m)
{
  int i = blockIdx.x * blockDim.x + threadIdx.x;
  if (i < m) {
    size_t s = (size_t)sidx[i];
    out[(size_t)i * 3 + 0] = point[s * 3 + 0];
    out[(size_t)i * 3 + 1] = point[s * 3 + 1];
    out[(size_t)i * 3 + 2] = point[s * 3 + 2];
  }
}

extern "C" void kernel_launch(void* const* d_in, const int* in_sizes, int n_in,
                              void* d_out, int out_size, void* d_ws, size_t ws_size,
                              hipStream_t stream)
{
  const float* point = (const float*)d_in[0];
  const float* feat  = (const float*)d_in[1];
  const float* W     = (const float*)d_in[2];
  const float* gamma = (const float*)d_in[3];
  const float* beta  = (const float*)d_in[4];
  const int* sample_idx = (const int*)d_in[5];
  const int* knn_idx    = (const int*)d_in[6];

  const int m = in_sizes[5];            // 60000
  const int k = in_sizes[6] / m;        // 16
  const int nTiles = m / 4;             // 4 points (64 rows) per tile

  float* out  = (float*)d_out;
  float* newp = out;                    // (m,3)
  float* ymax = out + (size_t)m * 3;    // (m,128) pre-norm max, finished in-place

  // ws layout: [ab 1KB][partials G*1KB][ymin m*512B if it fits]
  char* ws = (char*)d_ws;
  float* ab = (float*)ws;
  int G = (int)((ws_size > 1024 ? ws_size - 1024 : 0) / 1024);
  if (G > 2048) G = 2048;
  if (G < 8) G = 8;
  if (G > nTiles) G = nTiles;
  float* partials = (float*)(ws + 1024);
  size_t off_ymin = 1024 + (size_t)G * 1024;
  int has_ymin = (ws_size >= off_ymin + (size_t)m * 512) ? 1 : 0;
  float* ymin = (float*)(ws + off_ymin);

  td_newpoint<<<(m + 255) / 256, 256, 0, stream>>>(point, sample_idx, newp, m);
  td_main<<<G, 256, 0, stream>>>(point, feat, W, sample_idx, knn_idx,
                                 ymax, ymin, partials, nTiles, has_ymin);
  float invN = 1.0f / ((float)m * (float)k);
  td_stats<<<128, 256, 0, stream>>>(partials, gamma, beta, ab, G, invN);
  td_transform<<<2048, 256, 0, stream>>>(ymax, ymin, ab, m * 128 / 4, has_ymin);
}